// Round 6
// baseline (2805.806 us; speedup 1.0000x reference)
//
#include <hip/hip_runtime.h>
#include <hip/hip_fp16.h>

// DAG phenotype evaluation: sentinel dataflow + watermark + CHUNKED claims.
//
// Round-6 change: the claim counter counts CHUNKS of 4 consecutive nodes.
// Round 5 measured ~13-15 ns per serialized same-line coherence-point op
// (claim counter: ~101k ops = 1.3 ms = the whole runtime). Chunking divides
// every control-line op (claim atomic, WM read, page atomic, vmcnt drain)
// by 4, and adds cross-node ILP: all 4 nodes' plain-cached gathers are
// issued upfront; in-chunk preds forward from registers (lane l owns slot l
// of every row, so the producer lane's packed output IS the needed word).
//
// vals[N_NODES][64]: packed half2(b, b+64), 256 B/row. SENTW = NaN|NaN =
// "not ready". Producers publish with coherent write-through stores; after
// draining a chunk's stores (vmcnt(0)), lane 0 adds CHUNK to its page
// counter; the filler of a page CAS-advances watermark WM ("all < WM done").
// Consumers gather preds < WM with PLAIN CACHED loads (L2-allocating),
// preds >= WM via coherent sentinel poll with s_sleep backoff.
//
// Plain-load staleness safety: plain loads only ever target rows already
// final; coherent ops bypass/don't allocate L2, so consumer L2s never hold
// a stale line of a row that later changes. asm volatile prevents hoisting
// above the WM branch; vmcnt(0)+sched_barrier(0) before first use.
//
// Deadlock-freedom (chunked): chunks are claimed in increasing order. Let m
// be the lowest uncomputed node, in chunk C. If C is claimed, its holder
// already computed C's nodes before m (all < m), so it is polling m, whose
// preds (< m, or in-chunk registers) are ready -> progress. If C is
// unclaimed, all claimed chunks precede C, their holders' polls succeed as
// above, and one of them will claim C. No co-residency assumption.

#define N_NODES 100000
#define N_IN    1024
#define N_OUT   1024
#define FAN_IN  32
#define NPAIR   64              // BATCH/2 packed slots per row
#define N_TODO  (N_NODES - N_IN)
#define SENTW   0xFFFFFFFFu
#define CHUNK   4
#define NCHUNK  (N_TODO / CHUNK)   // 24744 (exact)
#define PGSZ    1024
#define PGSHIFT 10
#define NPAGES  ((N_TODO + PGSZ - 1) / PGSZ)   // 97

// ws layout (bytes) — every control word on its own padded region:
//   [0]      claim counter (chunks)
//   [4096]   wm_page
//   [8192]   page_cnt[97], stride 256 B (64 ints)
//   [65536]  vals (25.6 MB)
#define OFS_WM    4096
#define OFS_PC    8192
#define PC_STRIDE 64
#define OFS_VALS  65536

__global__ __launch_bounds__(256) void init_kernel(const float* __restrict__ x,
                                                   unsigned* __restrict__ vals,
                                                   int* __restrict__ counter,
                                                   int* __restrict__ wm_page,
                                                   int* __restrict__ page_cnt) {
    const int tid = blockIdx.x * blockDim.x + threadIdx.x;
    if (tid == 0) { *counter = 0; *wm_page = 0; }
    if (tid < NPAGES) page_cnt[tid * PC_STRIDE] = 0;
    if (tid < N_IN * NPAIR) {
        const int i = tid >> 6;
        const int b = tid & 63;
        __half2 h2 = __floats2half2_rn(x[b * N_IN + i], x[(b + 64) * N_IN + i]);
        vals[i * NPAIR + b] = *reinterpret_cast<unsigned*>(&h2);
    }
    uint4* p = (uint4*)(vals + (size_t)N_IN * NPAIR);
    const int total = N_TODO * NPAIR / 4;
    const uint4 s4 = make_uint4(SENTW, SENTW, SENTW, SENTW);
    for (int t = tid; t < total; t += gridDim.x * blockDim.x)
        p[t] = s4;
}

__global__ __launch_bounds__(256, 2) void dag_kernel(const float* __restrict__ weights,
                                                     const int* __restrict__ in_ids,
                                                     unsigned* __restrict__ vals,
                                                     int* __restrict__ counter,
                                                     int* __restrict__ wm_page,
                                                     int* __restrict__ page_cnt,
                                                     float* __restrict__ out) {
    const int lane = threadIdx.x & 63;

    int c = 0;
    if (lane == 0) c = atomicAdd(counter, 1);
    c = __builtin_amdgcn_readfirstlane(c);

    while (c < NCHUNK) {
        int nxt = 0;
        if (lane == 0) nxt = atomicAdd(counter, 1);

        const int n0 = N_IN + c * CHUNK;      // first node of chunk

        // one WM read per chunk (dedicated line)
        int wmp = __hip_atomic_load(wm_page, __ATOMIC_RELAXED, __HIP_MEMORY_SCOPE_AGENT);
        const int wmn = __builtin_amdgcn_readfirstlane(N_IN + (wmp << PGSHIFT));

        // classify all 4*32 preds; issue plain cached loads upfront (bulk)
        unsigned v[CHUNK][FAN_IN];
        unsigned inchunk[CHUNK], cohm[CHUNK];
#pragma unroll
        for (int j = 0; j < CHUNK; ++j) {
            inchunk[j] = 0; cohm[j] = 0;
            const long wb = (long)(n0 + j) * FAN_IN;
#pragma unroll
            for (int k = 0; k < FAN_IN; ++k) {
                const int id = in_ids[wb + k];           // uniform s_load
                if (id >= n0) {
                    inchunk[j] |= 1u << k;               // register forward later
                } else if (id < wmn) {
                    const unsigned* p = vals + (long)id * NPAIR + lane;
                    asm volatile("global_load_dword %0, %1, off"
                                 : "=v"(v[j][k]) : "v"(p));
                } else {
                    cohm[j] |= 1u << k;                  // coherent poll later
                }
            }
        }
        asm volatile("s_waitcnt vmcnt(0)" ::: "memory");
        __builtin_amdgcn_sched_barrier(0);

        unsigned outp[CHUNK];
#pragma unroll
        for (int j = 0; j < CHUNK; ++j) {
            const long wb = (long)(n0 + j) * FAN_IN;

            // in-chunk preds: forward producer lane's own packed output
            if (inchunk[j]) {
#pragma unroll
                for (int k = 0; k < FAN_IN; ++k)
                    if ((inchunk[j] >> k) & 1u) {
                        const int jj = in_ids[wb + k] - n0;   // uniform, < j
                        unsigned f = outp[0];
                        if (jj == 1) f = (j > 1) ? outp[1] : f;
                        if (jj == 2) f = (j > 2) ? outp[2] : f;
                        v[j][k] = f;
                    }
            }

            // coherent sentinel poll over the >=WM subset
            unsigned need = cohm[j];
            bool first = true;
            while (need) {
                if (!first) __builtin_amdgcn_s_sleep(1);
                first = false;
#pragma unroll
                for (int k = 0; k < FAN_IN; ++k)
                    if ((need >> k) & 1u) {
                        const int id = in_ids[wb + k];
                        v[j][k] = __hip_atomic_load(vals + (long)id * NPAIR + lane,
                                                    __ATOMIC_RELAXED,
                                                    __HIP_MEMORY_SCOPE_AGENT);
                    }
                unsigned got = 0;
#pragma unroll
                for (int k = 0; k < FAN_IN; ++k)
                    if ((need >> k) & 1u)
                        if (__all(v[j][k] != SENTW)) got |= 1u << k;
                need &= ~got;
            }

            // dot + relu in fp32 (weights uniform -> SGPR operand)
            float acc0 = 0.f, acc1 = 0.f;
#pragma unroll
            for (int k = 0; k < FAN_IN; ++k) {
                const float  wk = weights[wb + k];
                const __half2 h2 = *reinterpret_cast<const __half2*>(&v[j][k]);
                const float2  f  = __half22float2(h2);
                acc0 = fmaf(wk, f.x, acc0);
                acc1 = fmaf(wk, f.y, acc1);
            }
            acc0 = fmaxf(acc0, 0.f);
            acc1 = fmaxf(acc1, 0.f);

            // publish (coherent write-through)
            __half2 hr = __floats2half2_rn(acc0, acc1);
            outp[j] = *reinterpret_cast<unsigned*>(&hr);
            __hip_atomic_store(vals + (long)(n0 + j) * NPAIR + lane, outp[j],
                               __ATOMIC_RELAXED, __HIP_MEMORY_SCOPE_AGENT);

            // output-layer scatter
            const int node = n0 + j;
            if (node >= N_NODES - N_OUT) {
                const int jo = node - (N_NODES - N_OUT);
                out[lane * N_OUT + jo]        = acc0;
                out[(lane + 64) * N_OUT + jo] = acc1;
            }
        }

        // page accounting once per chunk (values drained to coherence point)
        asm volatile("s_waitcnt vmcnt(0)" ::: "memory");
        if (lane == 0) {
            const int pg = (c * CHUNK) >> PGSHIFT;       // chunk fits one page
            const int ps = min(PGSZ, N_TODO - (pg << PGSHIFT));
            int old = __hip_atomic_fetch_add(page_cnt + (size_t)pg * PC_STRIDE, CHUNK,
                                             __ATOMIC_RELAXED, __HIP_MEMORY_SCOPE_AGENT);
            if (old + CHUNK == ps) {
                for (;;) {   // advance WM over all consecutively-full pages
                    int cur = __hip_atomic_load(wm_page, __ATOMIC_RELAXED,
                                                __HIP_MEMORY_SCOPE_AGENT);
                    if (cur >= NPAGES) break;
                    int fps = min(PGSZ, N_TODO - (cur << PGSHIFT));
                    int cnt = __hip_atomic_load(page_cnt + (size_t)cur * PC_STRIDE,
                                                __ATOMIC_RELAXED, __HIP_MEMORY_SCOPE_AGENT);
                    if (cnt < fps) break;
                    int expected = cur;
                    __hip_atomic_compare_exchange_strong(wm_page, &expected, cur + 1,
                                                         __ATOMIC_RELAXED, __ATOMIC_RELAXED,
                                                         __HIP_MEMORY_SCOPE_AGENT);
                }
            }
        }

        c = __builtin_amdgcn_readfirstlane(nxt);
    }
}

extern "C" void kernel_launch(void* const* d_in, const int* in_sizes, int n_in,
                              void* d_out, int out_size, void* d_ws, size_t ws_size,
                              hipStream_t stream) {
    const float* x       = (const float*)d_in[0];
    const float* weights = (const float*)d_in[1];
    const int*   in_ids  = (const int*)d_in[2];
    float*       out     = (float*)d_out;

    int*      counter = (int*)d_ws;
    int*      wm_page = (int*)((char*)d_ws + OFS_WM);
    int*      page_cnt= (int*)((char*)d_ws + OFS_PC);
    unsigned* vals    = (unsigned*)((char*)d_ws + OFS_VALS);

    init_kernel<<<2048, 256, 0, stream>>>(x, vals, counter, wm_page, page_cnt);
    // 512 blocks x 256 threads = 2048 waves; window = 2048*CHUNK = 8192 nodes
    dag_kernel<<<512, 256, 0, stream>>>(weights, in_ids, vals, counter,
                                        wm_page, page_cnt, out);
}

// Round 7
// 1428.708 us; speedup vs baseline: 1.9639x; 1.9639x over previous
//
#include <hip/hip_runtime.h>
#include <hip/hip_fp16.h>

// DAG phenotype evaluation: sentinel dataflow + watermark + BLOCK-PARALLEL
// group claiming.
//
// Round-7: one block claims a GROUP of 4 consecutive nodes; its 4 waves
// compute them IN PARALLEL (round 6 serialized them in one wave -> depth
// x4 = regression). Control-line ops stay amortized x4 (1 claim atomic,
// 1 WM read, 1 page atomic per group), and the claim window shrinks to
// 256 blocks x 4 = 1024 nodes, so for most of the array a node's max-index
// pred (gap ~ i/33 > 1024 for i > 34k) is COMPLETE before the node is even
// claimed -> waves gather at full throughput instead of idling blocked
// (round 5: 2048-node window -> 26.7 us/iter mostly blocked, 2% VALUBusy).
//
// vals[N_NODES][64]: packed half2(b, b+64), 256 B/row. SENTW = NaN|NaN =
// "not ready". Producers publish with coherent write-through stores, drain
// vmcnt(0), block-barrier, then thread 0 adds GROUP to the page counter;
// the filler of a page CAS-advances watermark WM ("all < WM done").
// Consumers gather preds < WM with PLAIN CACHED loads (L2-allocating,
// the bulk), preds >= WM via coherent sentinel poll with s_sleep backoff.
//
// Plain-load staleness safety: plain loads only target rows already final
// (WM-guarded); coherent ops don't allocate into L2, so no stale line of a
// still-changing row can sit in a consumer L2. asm volatile prevents
// hoisting above the WM branch; vmcnt(0)+sched_barrier(0) before use.
//
// Deadlock-freedom: groups are claimed in increasing order. The lowest
// uncomputed node m is in a claimed group (or the next claim); its preds
// are all < m, hence complete; the wave holding m is polling and will
// detect them -> m completes. Induction. In-group deps (pred in same
// group) resolve through the same coherent store->poll path. No
// co-residency assumption; block barriers involve only one block's waves,
// each of which terminates its poll by the same induction.

#define N_NODES 100000
#define N_IN    1024
#define N_OUT   1024
#define FAN_IN  32
#define NPAIR   64              // BATCH/2 packed slots per row
#define N_TODO  (N_NODES - N_IN)
#define SENTW   0xFFFFFFFFu
#define GROUP   4
#define NGROUP  (N_TODO / GROUP)   // 24744 (exact)
#define PGSZ    1024
#define PGSHIFT 10
#define NPAGES  ((N_TODO + PGSZ - 1) / PGSZ)   // 97

// ws layout (bytes) — every control word on its own padded region:
//   [0]      claim counter (groups)
//   [4096]   wm_page
//   [8192]   page_cnt[97], stride 256 B (64 ints)
//   [65536]  vals (25.6 MB)
#define OFS_WM    4096
#define OFS_PC    8192
#define PC_STRIDE 64
#define OFS_VALS  65536

__global__ __launch_bounds__(256) void init_kernel(const float* __restrict__ x,
                                                   unsigned* __restrict__ vals,
                                                   int* __restrict__ counter,
                                                   int* __restrict__ wm_page,
                                                   int* __restrict__ page_cnt) {
    const int tid = blockIdx.x * blockDim.x + threadIdx.x;
    if (tid == 0) { *counter = 0; *wm_page = 0; }
    if (tid < NPAGES) page_cnt[tid * PC_STRIDE] = 0;
    if (tid < N_IN * NPAIR) {
        const int i = tid >> 6;
        const int b = tid & 63;
        __half2 h2 = __floats2half2_rn(x[b * N_IN + i], x[(b + 64) * N_IN + i]);
        vals[i * NPAIR + b] = *reinterpret_cast<unsigned*>(&h2);
    }
    uint4* p = (uint4*)(vals + (size_t)N_IN * NPAIR);
    const int total = N_TODO * NPAIR / 4;
    const uint4 s4 = make_uint4(SENTW, SENTW, SENTW, SENTW);
    for (int t = tid; t < total; t += gridDim.x * blockDim.x)
        p[t] = s4;
}

__global__ __launch_bounds__(256, 1) void dag_kernel(const float* __restrict__ weights,
                                                     const int* __restrict__ in_ids,
                                                     unsigned* __restrict__ vals,
                                                     int* __restrict__ counter,
                                                     int* __restrict__ wm_page,
                                                     int* __restrict__ page_cnt,
                                                     float* __restrict__ out) {
    __shared__ int lds_g, lds_wm;
    const int tid  = threadIdx.x;
    const int wv   = tid >> 6;      // wave 0..3 -> node offset in group
    const int lane = tid & 63;

    for (;;) {
        if (tid == 0) {
            lds_g  = atomicAdd(counter, 1);
            lds_wm = __hip_atomic_load(wm_page, __ATOMIC_RELAXED,
                                       __HIP_MEMORY_SCOPE_AGENT);
        }
        __syncthreads();
        const int g = lds_g;
        if (g >= NGROUP) return;
        const int wmn = N_IN + (lds_wm << PGSHIFT);

        const int  node = N_IN + g * GROUP + wv;
        const long wb   = (long)node * FAN_IN;

        int ids[FAN_IN];
#pragma unroll
        for (int k = 0; k < FAN_IN; ++k)
            ids[k] = in_ids[wb + k];             // uniform -> s_load

        // split gather: plain cached loads (<WM, bulk) vs coherent (>=WM)
        unsigned v[FAN_IN];
        unsigned need = 0;                        // uniform bitmask
#pragma unroll
        for (int k = 0; k < FAN_IN; ++k) {
            const unsigned* p = vals + (long)ids[k] * NPAIR + lane;
            if (ids[k] < wmn) {
                asm volatile("global_load_dword %0, %1, off"
                             : "=v"(v[k]) : "v"(p));
            } else {
                v[k] = __hip_atomic_load(p, __ATOMIC_RELAXED,
                                         __HIP_MEMORY_SCOPE_AGENT);
                need |= 1u << k;
            }
        }
        asm volatile("s_waitcnt vmcnt(0)" ::: "memory");
        __builtin_amdgcn_sched_barrier(0);

        // sentinel poll with light backoff over the coherent subset
        while (need) {
            unsigned got = 0;
#pragma unroll
            for (int k = 0; k < FAN_IN; ++k)
                if ((need >> k) & 1u)
                    if (__all(v[k] != SENTW)) got |= 1u << k;
            need &= ~got;
            if (!need) break;
            __builtin_amdgcn_s_sleep(1);
#pragma unroll
            for (int k = 0; k < FAN_IN; ++k)
                if ((need >> k) & 1u)
                    v[k] = __hip_atomic_load(vals + (long)ids[k] * NPAIR + lane,
                                             __ATOMIC_RELAXED,
                                             __HIP_MEMORY_SCOPE_AGENT);
        }

        // dot + relu in fp32 (weights uniform -> SGPR operand)
        float acc0 = 0.f, acc1 = 0.f;
#pragma unroll
        for (int k = 0; k < FAN_IN; ++k) {
            const float  wk = weights[wb + k];
            const __half2 h2 = *reinterpret_cast<const __half2*>(&v[k]);
            const float2  f  = __half22float2(h2);
            acc0 = fmaf(wk, f.x, acc0);
            acc1 = fmaf(wk, f.y, acc1);
        }
        acc0 = fmaxf(acc0, 0.f);
        acc1 = fmaxf(acc1, 0.f);

        // publish (coherent write-through)
        __half2 hr = __floats2half2_rn(acc0, acc1);
        __hip_atomic_store(vals + (long)node * NPAIR + lane,
                           *reinterpret_cast<unsigned*>(&hr),
                           __ATOMIC_RELAXED, __HIP_MEMORY_SCOPE_AGENT);

        // output-layer scatter
        if (node >= N_NODES - N_OUT) {
            const int jo = node - (N_NODES - N_OUT);
            out[lane * N_OUT + jo]        = acc0;
            out[(lane + 64) * N_OUT + jo] = acc1;
        }

        // drain own publish, then block-wide barrier, then one page atomic
        asm volatile("s_waitcnt vmcnt(0)" ::: "memory");
        __syncthreads();
        if (tid == 0) {
            const int pg = (g * GROUP) >> PGSHIFT;   // group never crosses a page
            const int ps = min(PGSZ, N_TODO - (pg << PGSHIFT));
            int old = __hip_atomic_fetch_add(page_cnt + (size_t)pg * PC_STRIDE, GROUP,
                                             __ATOMIC_RELAXED, __HIP_MEMORY_SCOPE_AGENT);
            if (old + GROUP == ps) {
                for (;;) {   // advance WM over all consecutively-full pages
                    int cur = __hip_atomic_load(wm_page, __ATOMIC_RELAXED,
                                                __HIP_MEMORY_SCOPE_AGENT);
                    if (cur >= NPAGES) break;
                    int fps = min(PGSZ, N_TODO - (cur << PGSHIFT));
                    int cnt = __hip_atomic_load(page_cnt + (size_t)cur * PC_STRIDE,
                                                __ATOMIC_RELAXED,
                                                __HIP_MEMORY_SCOPE_AGENT);
                    if (cnt < fps) break;
                    int expected = cur;
                    __hip_atomic_compare_exchange_strong(wm_page, &expected, cur + 1,
                                                         __ATOMIC_RELAXED, __ATOMIC_RELAXED,
                                                         __HIP_MEMORY_SCOPE_AGENT);
                }
            }
        }
    }
}

extern "C" void kernel_launch(void* const* d_in, const int* in_sizes, int n_in,
                              void* d_out, int out_size, void* d_ws, size_t ws_size,
                              hipStream_t stream) {
    const float* x       = (const float*)d_in[0];
    const float* weights = (const float*)d_in[1];
    const int*   in_ids  = (const int*)d_in[2];
    float*       out     = (float*)d_out;

    int*      counter = (int*)d_ws;
    int*      wm_page = (int*)((char*)d_ws + OFS_WM);
    int*      page_cnt= (int*)((char*)d_ws + OFS_PC);
    unsigned* vals    = (unsigned*)((char*)d_ws + OFS_VALS);

    init_kernel<<<2048, 256, 0, stream>>>(x, vals, counter, wm_page, page_cnt);
    // 256 blocks x 4 waves: window = 1024 nodes, claims stay at the frontier
    dag_kernel<<<256, 256, 0, stream>>>(weights, in_ids, vals, counter,
                                        wm_page, page_cnt, out);
}

// Round 8
// 1056.911 us; speedup vs baseline: 2.6547x; 1.3518x over previous
//
#include <hip/hip_runtime.h>
#include <hip/hip_fp16.h>

// DAG phenotype evaluation: sentinel dataflow + watermark + STATIC ownership.
//
// Round-8: wave w (of NW=1024) statically owns nodes N_IN + w + t*NW, in
// increasing t. Eliminates the claim counter (round 5 measured ~13-15 ns per
// serialized op on that one line), all block barriers (round 7's lockstep),
// and defers the page-counter fetch_add's RESULT consumption by one node so
// the contended-line latency is off every wave's serial path.
//
// vals[N_NODES][64]: packed half2(b, b+64), 256 B/row. SENTW = NaN|NaN =
// "not ready". Producers publish with coherent write-through stores, drain
// vmcnt(0), then lane0 fetch_adds the node's page counter (result checked
// next iteration); the filler of a page CAS-advances watermark WM ("all
// < WM done"). Consumers gather preds < WM with PLAIN CACHED loads
// (L2-allocating, bulk), preds >= WM via coherent sentinel poll.
//
// Plain-load safety: plain loads only target rows already final (WM-guarded;
// WM read once per node is a lower bound of true WM). vals rows are 256B-
// aligned, so any line a plain load allocates contains only final data.
// asm volatile prevents hoisting above the WM branch; vmcnt(0)+sched_barrier
// before use. WM lag cannot deadlock: polls are correct without WM.
//
// Deadlock-freedom: 256 blocks <= 256 CUs -> all waves dispatched. Waves
// process own nodes in increasing index order. Lowest uncomputed node m:
// its owner's current node j <= m has all preds < j <= m computed, so its
// poll terminates -> j completes -> induction reaches and completes m.

#define N_NODES 100000
#define N_IN    1024
#define N_OUT   1024
#define FAN_IN  32
#define NPAIR   64              // BATCH/2 packed slots per row
#define N_TODO  (N_NODES - N_IN)
#define SENTW   0xFFFFFFFFu
#define NW      1024            // static owner waves
#define PGSZ    1024
#define PGSHIFT 10
#define NPAGES  ((N_TODO + PGSZ - 1) / PGSZ)   // 97

// ws layout (bytes) — every control word on its own padded region:
//   [4096]   wm_page
//   [8192]   page_cnt[97], stride 256 B (64 ints)
//   [65536]  vals (25.6 MB)
#define OFS_WM    4096
#define OFS_PC    8192
#define PC_STRIDE 64
#define OFS_VALS  65536

__global__ __launch_bounds__(256) void init_kernel(const float* __restrict__ x,
                                                   unsigned* __restrict__ vals,
                                                   int* __restrict__ wm_page,
                                                   int* __restrict__ page_cnt) {
    const int tid = blockIdx.x * blockDim.x + threadIdx.x;
    if (tid == 0) *wm_page = 0;
    if (tid < NPAGES) page_cnt[tid * PC_STRIDE] = 0;
    if (tid < N_IN * NPAIR) {
        const int i = tid >> 6;
        const int b = tid & 63;
        __half2 h2 = __floats2half2_rn(x[b * N_IN + i], x[(b + 64) * N_IN + i]);
        vals[i * NPAIR + b] = *reinterpret_cast<unsigned*>(&h2);
    }
    uint4* p = (uint4*)(vals + (size_t)N_IN * NPAIR);
    const int total = N_TODO * NPAIR / 4;
    const uint4 s4 = make_uint4(SENTW, SENTW, SENTW, SENTW);
    for (int t = tid; t < total; t += gridDim.x * blockDim.x)
        p[t] = s4;
}

__device__ __forceinline__ void wm_advance(int* wm_page, int* page_cnt) {
    for (;;) {   // advance WM over all consecutively-full pages
        int cur = __hip_atomic_load(wm_page, __ATOMIC_RELAXED,
                                    __HIP_MEMORY_SCOPE_AGENT);
        if (cur >= NPAGES) break;
        int fps = min(PGSZ, N_TODO - (cur << PGSHIFT));
        int cnt = __hip_atomic_load(page_cnt + (size_t)cur * PC_STRIDE,
                                    __ATOMIC_RELAXED, __HIP_MEMORY_SCOPE_AGENT);
        if (cnt < fps) break;
        int expected = cur;
        __hip_atomic_compare_exchange_strong(wm_page, &expected, cur + 1,
                                             __ATOMIC_RELAXED, __ATOMIC_RELAXED,
                                             __HIP_MEMORY_SCOPE_AGENT);
    }
}

__global__ __launch_bounds__(256, 1) void dag_kernel(const float* __restrict__ weights,
                                                     const int* __restrict__ in_ids,
                                                     unsigned* __restrict__ vals,
                                                     int* __restrict__ wm_page,
                                                     int* __restrict__ page_cnt,
                                                     float* __restrict__ out) {
    const int tid  = threadIdx.x;
    const int lane = tid & 63;
    const int w    = __builtin_amdgcn_readfirstlane(blockIdx.x * 4 + (tid >> 6));

    int pend_pg  = -1;   // page whose fetch_add result is pending (uniform)
    int pend_old = 0;    // lane0's pending fetch_add result

    for (int t = 0;; ++t) {
        const int node = N_IN + t * NW + w;
        if (node >= N_NODES) break;

        // WM read (coherent, dedicated line) — lower bound of true WM
        int wmp = __hip_atomic_load(wm_page, __ATOMIC_RELAXED,
                                    __HIP_MEMORY_SCOPE_AGENT);
        const int wmn = __builtin_amdgcn_readfirstlane(N_IN + (wmp << PGSHIFT));

        const long wb = (long)node * FAN_IN;
        int ids[FAN_IN];
#pragma unroll
        for (int k = 0; k < FAN_IN; ++k)
            ids[k] = in_ids[wb + k];             // uniform

        // split gather: plain cached (<WM, bulk) vs coherent (>=WM)
        unsigned v[FAN_IN];
        unsigned need = 0;                        // uniform bitmask
#pragma unroll
        for (int k = 0; k < FAN_IN; ++k) {
            const unsigned* p = vals + (long)ids[k] * NPAIR + lane;
            if (ids[k] < wmn) {
                asm volatile("global_load_dword %0, %1, off"
                             : "=v"(v[k]) : "v"(p));
            } else {
                v[k] = __hip_atomic_load(p, __ATOMIC_RELAXED,
                                         __HIP_MEMORY_SCOPE_AGENT);
                need |= 1u << k;
            }
        }
        asm volatile("s_waitcnt vmcnt(0)" ::: "memory");
        __builtin_amdgcn_sched_barrier(0);

        // deferred page-fill check from the PREVIOUS node (result is now
        // certainly back; runs BEFORE our poll so WM advance isn't delayed)
        if (pend_pg >= 0) {
            if (lane == 0) {
                const int ps = min(PGSZ, N_TODO - (pend_pg << PGSHIFT));
                if (pend_old + 1 == ps) wm_advance(wm_page, page_cnt);
            }
            pend_pg = -1;
        }

        // sentinel poll over the coherent subset (light backoff)
        while (need) {
            unsigned got = 0;
#pragma unroll
            for (int k = 0; k < FAN_IN; ++k)
                if ((need >> k) & 1u)
                    if (__all(v[k] != SENTW)) got |= 1u << k;
            need &= ~got;
            if (!need) break;
            __builtin_amdgcn_s_sleep(1);
#pragma unroll
            for (int k = 0; k < FAN_IN; ++k)
                if ((need >> k) & 1u)
                    v[k] = __hip_atomic_load(vals + (long)ids[k] * NPAIR + lane,
                                             __ATOMIC_RELAXED,
                                             __HIP_MEMORY_SCOPE_AGENT);
        }

        // dot + relu in fp32 (weights uniform -> SGPR operand)
        float acc0 = 0.f, acc1 = 0.f;
#pragma unroll
        for (int k = 0; k < FAN_IN; ++k) {
            const float  wk = weights[wb + k];
            const __half2 h2 = *reinterpret_cast<const __half2*>(&v[k]);
            const float2  f  = __half22float2(h2);
            acc0 = fmaf(wk, f.x, acc0);
            acc1 = fmaf(wk, f.y, acc1);
        }
        acc0 = fmaxf(acc0, 0.f);
        acc1 = fmaxf(acc1, 0.f);

        // publish (coherent write-through)
        __half2 hr = __floats2half2_rn(acc0, acc1);
        __hip_atomic_store(vals + (long)node * NPAIR + lane,
                           *reinterpret_cast<unsigned*>(&hr),
                           __ATOMIC_RELAXED, __HIP_MEMORY_SCOPE_AGENT);

        // output-layer scatter
        if (node >= N_NODES - N_OUT) {
            const int jo = node - (N_NODES - N_OUT);
            out[lane * N_OUT + jo]        = acc0;
            out[(lane + 64) * N_OUT + jo] = acc1;
        }

        // drain publish to the coherence point, then count it (fire the
        // atomic now; its RESULT is consumed next iteration)
        asm volatile("s_waitcnt vmcnt(0)" ::: "memory");
        const int pg = (node - N_IN) >> PGSHIFT;
        if (lane == 0)
            pend_old = __hip_atomic_fetch_add(page_cnt + (size_t)pg * PC_STRIDE, 1,
                                              __ATOMIC_RELAXED,
                                              __HIP_MEMORY_SCOPE_AGENT);
        pend_pg = pg;
    }

    // final pending page-fill check
    if (pend_pg >= 0 && lane == 0) {
        const int ps = min(PGSZ, N_TODO - (pend_pg << PGSHIFT));
        if (pend_old + 1 == ps) wm_advance(wm_page, page_cnt);
    }
}

extern "C" void kernel_launch(void* const* d_in, const int* in_sizes, int n_in,
                              void* d_out, int out_size, void* d_ws, size_t ws_size,
                              hipStream_t stream) {
    const float* x       = (const float*)d_in[0];
    const float* weights = (const float*)d_in[1];
    const int*   in_ids  = (const int*)d_in[2];
    float*       out     = (float*)d_out;

    int*      wm_page = (int*)((char*)d_ws + OFS_WM);
    int*      page_cnt= (int*)((char*)d_ws + OFS_PC);
    unsigned* vals    = (unsigned*)((char*)d_ws + OFS_VALS);

    init_kernel<<<2048, 256, 0, stream>>>(x, vals, wm_page, page_cnt);
    // 256 blocks x 4 waves = NW=1024 static owner waves (1 block/CU -> all
    // dispatched immediately; no co-residency assumption needed)
    dag_kernel<<<256, 256, 0, stream>>>(weights, in_ids, vals,
                                        wm_page, page_cnt, out);
}

// Round 9
// 681.667 us; speedup vs baseline: 4.1161x; 1.5505x over previous
//
#include <hip/hip_runtime.h>
#include <hip/hip_fp16.h>

// DAG phenotype evaluation: sentinel dataflow + watermark + static ownership
// + FULL SOFTWARE PIPELINE (round 9).
//
// Wave w (of NW=1024) owns nodes N_IN + w + t*NW in increasing t. Per
// iteration the ONLY waits are (a) one vmcnt(0) draining work issued a full
// node-duration earlier (usually free) and (b) the irreducible dependency
// poll. Everything that was result-blocking in round 8 is deferred:
//   - gather(t+1) (32 pred loads + WM load, exactly 33 asm VMEM ops) is
//     issued at the END of iteration t -> latency hidden under iter t+1.
//   - WM used for classification is one node stale (lower bound = safe).
//   - page fetch_add for node t is issued at iter t+1 AFTER vmcnt(0) (which
//     drained t's publish stores -> store->count ordering for free); its
//     result is checked at iter t+2.
//
// vals[N_NODES][64]: packed half2(b, b+64), 256 B/row. SENTW = NaN|NaN =
// "not ready". Publishes are agent-coherent stores (sc0 sc1, write-through
// to the L3 coherence point). Preds < WM gather via PLAIN cached loads
// (L2-allocating, bulk); preds >= WM via coherent sentinel poll with
// s_sleep backoff. Plain loads only target rows already final (WM-guarded),
// so consumer caches never hold a stale line of a still-changing row.
//
// Deadlock-freedom: 256 blocks <= 256 CUs, 0 LDS -> all waves resident.
// Waves process own nodes in increasing order; lowest uncomputed node m:
// its owner's current node j <= m has all preds < j computed, so its poll
// terminates -> induction reaches m. WM lag cannot deadlock (polls are
// correct without WM).

#define N_NODES 100000
#define N_IN    1024
#define N_OUT   1024
#define FAN_IN  32
#define NPAIR   64              // BATCH/2 packed slots per row
#define N_TODO  (N_NODES - N_IN)
#define SENTW   0xFFFFFFFFu
#define NW      1024            // static owner waves
#define PGSZ    1024
#define PGSHIFT 10
#define NPAGES  ((N_TODO + PGSZ - 1) / PGSZ)   // 97

// ws layout (bytes) — every control word on its own padded region:
//   [4096]   wm_page
//   [8192]   page_cnt[97], stride 256 B (64 ints)
//   [65536]  vals (25.6 MB)
#define OFS_WM    4096
#define OFS_PC    8192
#define PC_STRIDE 64
#define OFS_VALS  65536

__global__ __launch_bounds__(256) void init_kernel(const float* __restrict__ x,
                                                   unsigned* __restrict__ vals,
                                                   int* __restrict__ wm_page,
                                                   int* __restrict__ page_cnt) {
    const int tid = blockIdx.x * blockDim.x + threadIdx.x;
    if (tid == 0) *wm_page = 0;
    if (tid < NPAGES) page_cnt[tid * PC_STRIDE] = 0;
    if (tid < N_IN * NPAIR) {
        const int i = tid >> 6;
        const int b = tid & 63;
        __half2 h2 = __floats2half2_rn(x[b * N_IN + i], x[(b + 64) * N_IN + i]);
        vals[i * NPAIR + b] = *reinterpret_cast<unsigned*>(&h2);
    }
    uint4* p = (uint4*)(vals + (size_t)N_IN * NPAIR);
    const int total = N_TODO * NPAIR / 4;
    const uint4 s4 = make_uint4(SENTW, SENTW, SENTW, SENTW);
    for (int t = tid; t < total; t += gridDim.x * blockDim.x)
        p[t] = s4;
}

__device__ __forceinline__ void wm_advance(int* wm_page, int* page_cnt) {
    for (;;) {   // advance WM over all consecutively-full pages
        int cur = __hip_atomic_load(wm_page, __ATOMIC_RELAXED,
                                    __HIP_MEMORY_SCOPE_AGENT);
        if (cur >= NPAGES) break;
        int fps = min(PGSZ, N_TODO - (cur << PGSHIFT));
        int cnt = __hip_atomic_load(page_cnt + (size_t)cur * PC_STRIDE,
                                    __ATOMIC_RELAXED, __HIP_MEMORY_SCOPE_AGENT);
        if (cnt < fps) break;
        int expected = cur;
        __hip_atomic_compare_exchange_strong(wm_page, &expected, cur + 1,
                                             __ATOMIC_RELAXED, __ATOMIC_RELAXED,
                                             __HIP_MEMORY_SCOPE_AGENT);
    }
}

__global__ __launch_bounds__(256, 1) void dag_kernel(const float* __restrict__ weights,
                                                     const int* __restrict__ in_ids,
                                                     unsigned* __restrict__ vals,
                                                     int* __restrict__ wm_page,
                                                     int* __restrict__ page_cnt,
                                                     float* __restrict__ out) {
    const int tid  = threadIdx.x;
    const int lane = tid & 63;
    const int w    = __builtin_amdgcn_readfirstlane(blockIdx.x * 4 + (tid >> 6));

    unsigned v[FAN_IN];          // in-flight / gathered pred values (cur node)
    unsigned wmv  = 0;           // asm-loaded wm_page (valid after vmcnt(0))
    unsigned cohm = 0;           // uniform bitmask: cur node's coherent-path preds
    int pend_pg = -1, pend_old = 0;

    int node = N_IN + w;         // first own node

    // prologue: issue gather(first) with wmn = N_IN (only inputs guaranteed)
    {
        const long wb = (long)node * FAN_IN;
#pragma unroll
        for (int k = 0; k < FAN_IN; ++k) {
            const int id = in_ids[wb + k];
            const unsigned* p = vals + (long)id * NPAIR + lane;
            if (id < N_IN) {
                asm volatile("global_load_dword %0, %1, off"
                             : "=v"(v[k]) : "v"(p));
            } else {
                asm volatile("global_load_dword %0, %1, off sc0 sc1"
                             : "=v"(v[k]) : "v"(p));
                cohm |= 1u << k;
            }
        }
        asm volatile("global_load_dword %0, %1, off sc0 sc1"
                     : "=v"(wmv) : "v"(wm_page));
    }

    for (;;) {
        // single wait: drains gather(cur)+WM load (issued one node ago),
        // prev node's publish stores, and the page atomic before that.
        asm volatile("s_waitcnt vmcnt(0)" ::: "memory");
        __builtin_amdgcn_sched_barrier(0);

        // deferred page-fill check (atomic issued last iteration, drained now)
        if (pend_pg >= 0) {
            if (lane == 0) {
                const int ps = min(PGSZ, N_TODO - (pend_pg << PGSHIFT));
                if (pend_old + 1 == ps) wm_advance(wm_page, page_cnt);
            }
            pend_pg = -1;
        }
        // issue page atomic for PREVIOUS own node (its stores are drained)
        if (node - NW >= N_IN) {
            const int ppg = (node - NW - N_IN) >> PGSHIFT;
            if (lane == 0)
                pend_old = __hip_atomic_fetch_add(page_cnt + (size_t)ppg * PC_STRIDE, 1,
                                                  __ATOMIC_RELAXED,
                                                  __HIP_MEMORY_SCOPE_AGENT);
            pend_pg = ppg;
        }

        // WM for classifying the NEXT node's gather (one node stale = safe)
        const int wmn = __builtin_amdgcn_readfirstlane((int)(N_IN + (wmv << PGSHIFT)));

        const long wb = (long)node * FAN_IN;

        // sentinel poll over the coherent subset (irreducible dependency wait)
        unsigned need = cohm;
        while (need) {
            unsigned got = 0;
#pragma unroll
            for (int k = 0; k < FAN_IN; ++k)
                if ((need >> k) & 1u)
                    if (__all(v[k] != SENTW)) got |= 1u << k;
            need &= ~got;
            if (!need) break;
            __builtin_amdgcn_s_sleep(1);
#pragma unroll
            for (int k = 0; k < FAN_IN; ++k)
                if ((need >> k) & 1u) {
                    const int id = in_ids[wb + k];
                    v[k] = __hip_atomic_load(vals + (long)id * NPAIR + lane,
                                             __ATOMIC_RELAXED,
                                             __HIP_MEMORY_SCOPE_AGENT);
                }
        }

        // dot + relu in fp32 (weights uniform -> SGPR operand)
        float acc0 = 0.f, acc1 = 0.f;
#pragma unroll
        for (int k = 0; k < FAN_IN; ++k) {
            const float  wk = weights[wb + k];
            const __half2 h2 = *reinterpret_cast<const __half2*>(&v[k]);
            const float2  f  = __half22float2(h2);
            acc0 = fmaf(wk, f.x, acc0);
            acc1 = fmaf(wk, f.y, acc1);
        }
        acc0 = fmaxf(acc0, 0.f);
        acc1 = fmaxf(acc1, 0.f);

        // publish (agent-coherent write-through store; no drain here)
        __half2 hr = __floats2half2_rn(acc0, acc1);
        const unsigned ow = *reinterpret_cast<const unsigned*>(&hr);
        unsigned* orow = vals + (long)node * NPAIR + lane;
        asm volatile("global_store_dword %0, %1, off sc0 sc1"
                     :: "v"(orow), "v"(ow));

        // output-layer scatter
        if (node >= N_NODES - N_OUT) {
            const int jo = node - (N_NODES - N_OUT);
            out[lane * N_OUT + jo]        = acc0;
            out[(lane + 64) * N_OUT + jo] = acc1;
        }

        const int nxt = node + NW;
        if (nxt >= N_NODES) break;

        // classify + issue gather(next): exactly 33 asm VMEM loads
        {
            const long wbn = (long)nxt * FAN_IN;
            unsigned cm = 0;
#pragma unroll
            for (int k = 0; k < FAN_IN; ++k) {
                const int id = in_ids[wbn + k];
                const unsigned* p = vals + (long)id * NPAIR + lane;
                if (id < wmn) {
                    asm volatile("global_load_dword %0, %1, off"
                                 : "=v"(v[k]) : "v"(p));
                } else {
                    asm volatile("global_load_dword %0, %1, off sc0 sc1"
                                 : "=v"(v[k]) : "v"(p));
                    cm |= 1u << k;
                }
            }
            asm volatile("global_load_dword %0, %1, off sc0 sc1"
                         : "=v"(wmv) : "v"(wm_page));
            cohm = cm;
        }
        node = nxt;
    }

    // epilogue: drain last publish, count last node, final WM checks
    asm volatile("s_waitcnt vmcnt(0)" ::: "memory");
    if (lane == 0) {
        if (pend_pg >= 0) {
            const int ps = min(PGSZ, N_TODO - (pend_pg << PGSHIFT));
            if (pend_old + 1 == ps) wm_advance(wm_page, page_cnt);
        }
        const int pg = (node - N_IN) >> PGSHIFT;
        const int ps = min(PGSZ, N_TODO - (pg << PGSHIFT));
        int old = __hip_atomic_fetch_add(page_cnt + (size_t)pg * PC_STRIDE, 1,
                                         __ATOMIC_RELAXED, __HIP_MEMORY_SCOPE_AGENT);
        if (old + 1 == ps) wm_advance(wm_page, page_cnt);
    }
}

extern "C" void kernel_launch(void* const* d_in, const int* in_sizes, int n_in,
                              void* d_out, int out_size, void* d_ws, size_t ws_size,
                              hipStream_t stream) {
    const float* x       = (const float*)d_in[0];
    const float* weights = (const float*)d_in[1];
    const int*   in_ids  = (const int*)d_in[2];
    float*       out     = (float*)d_out;

    int*      wm_page = (int*)((char*)d_ws + OFS_WM);
    int*      page_cnt= (int*)((char*)d_ws + OFS_PC);
    unsigned* vals    = (unsigned*)((char*)d_ws + OFS_VALS);

    init_kernel<<<2048, 256, 0, stream>>>(x, vals, wm_page, page_cnt);
    // 256 blocks x 4 waves = NW=1024 static owner waves, 1 block/CU ->
    // all resident; no co-residency assumption needed.
    dag_kernel<<<256, 256, 0, stream>>>(weights, in_ids, vals,
                                        wm_page, page_cnt, out);
}

// Round 10
// 564.495 us; speedup vs baseline: 4.9705x; 1.2076x over previous
//
#include <hip/hip_runtime.h>
#include <hip/hip_fp16.h>

// DAG phenotype evaluation: sentinel dataflow + watermark + static ownership
// + double-buffered prefetch-under-poll pipeline (round 10).
//
// Wave w (of NW=2048) owns nodes N_IN + w + t*NW in increasing t (48 rounds).
// Per iteration:
//   top:  vmcnt(0)  — drains prefetch(vn) issued a full iteration ago,
//                     prev publish stores, prev page atomic.
//         copy vn->v (safe: drained), cohm<-cmn
//         deferred page-fill check (t-2) ; issue page atomic (t-1)
//         issue prefetch gather(t+1) into vn  — latency hides under poll(t)
//   then: sentinel poll over v's coherent subset (irreducible dep wait),
//         dot+relu, coherent publish store (no drain), output scatter.
//
// vals[N_NODES][64]: packed half2(b, b+64), 256 B/row. SENTW = NaN|NaN =
// "not ready". Preds < WM (stale-by-one = safe lower bound) gather via PLAIN
// cached loads (L2-allocating, bulk); preds >= WM via agent-coherent loads
// (sc0 sc1) + sentinel poll with s_sleep backoff. Publishes are sc0 sc1
// write-through stores; page counters advance watermark WM via CAS.
// Plain loads only target rows already final (WM-guarded), so consumer
// caches never hold a stale line of a still-changing row.
//
// Deadlock-freedom: 512 blocks at __launch_bounds__(256,2), 0 LDS, ~120 VGPR
// -> 2 blocks/CU x 256 CUs = all 2048 waves resident. Waves process own
// nodes in increasing order; lowest uncomputed node m: its owner's current
// node j <= m has all preds < j computed, so its poll terminates ->
// induction reaches m. WM lag cannot deadlock (polls are correct without WM).

#define N_NODES 100000
#define N_IN    1024
#define N_OUT   1024
#define FAN_IN  32
#define NPAIR   64              // BATCH/2 packed slots per row
#define N_TODO  (N_NODES - N_IN)
#define SENTW   0xFFFFFFFFu
#define NW      2048            // static owner waves
#define NBLK    (NW / 4)        // 512 blocks
#define PGSZ    1024
#define PGSHIFT 10
#define NPAGES  ((N_TODO + PGSZ - 1) / PGSZ)   // 97

// ws layout (bytes) — every control word on its own padded region:
//   [4096]   wm_page
//   [8192]   page_cnt[97], stride 256 B (64 ints)
//   [65536]  vals (25.6 MB)
#define OFS_WM    4096
#define OFS_PC    8192
#define PC_STRIDE 64
#define OFS_VALS  65536

__global__ __launch_bounds__(256) void init_kernel(const float* __restrict__ x,
                                                   unsigned* __restrict__ vals,
                                                   int* __restrict__ wm_page,
                                                   int* __restrict__ page_cnt) {
    const int tid = blockIdx.x * blockDim.x + threadIdx.x;
    if (tid == 0) *wm_page = 0;
    if (tid < NPAGES) page_cnt[tid * PC_STRIDE] = 0;
    if (tid < N_IN * NPAIR) {
        const int i = tid >> 6;
        const int b = tid & 63;
        __half2 h2 = __floats2half2_rn(x[b * N_IN + i], x[(b + 64) * N_IN + i]);
        vals[i * NPAIR + b] = *reinterpret_cast<unsigned*>(&h2);
    }
    uint4* p = (uint4*)(vals + (size_t)N_IN * NPAIR);
    const int total = N_TODO * NPAIR / 4;
    const uint4 s4 = make_uint4(SENTW, SENTW, SENTW, SENTW);
    for (int t = tid; t < total; t += gridDim.x * blockDim.x)
        p[t] = s4;
}

__device__ __forceinline__ void wm_advance(int* wm_page, int* page_cnt) {
    for (;;) {   // advance WM over all consecutively-full pages
        int cur = __hip_atomic_load(wm_page, __ATOMIC_RELAXED,
                                    __HIP_MEMORY_SCOPE_AGENT);
        if (cur >= NPAGES) break;
        int fps = min(PGSZ, N_TODO - (cur << PGSHIFT));
        int cnt = __hip_atomic_load(page_cnt + (size_t)cur * PC_STRIDE,
                                    __ATOMIC_RELAXED, __HIP_MEMORY_SCOPE_AGENT);
        if (cnt < fps) break;
        int expected = cur;
        __hip_atomic_compare_exchange_strong(wm_page, &expected, cur + 1,
                                             __ATOMIC_RELAXED, __ATOMIC_RELAXED,
                                             __HIP_MEMORY_SCOPE_AGENT);
    }
}

__global__ __launch_bounds__(256, 2) void dag_kernel(const float* __restrict__ weights,
                                                     const int* __restrict__ in_ids,
                                                     unsigned* __restrict__ vals,
                                                     int* __restrict__ wm_page,
                                                     int* __restrict__ page_cnt,
                                                     float* __restrict__ out) {
    const int tid  = threadIdx.x;
    const int lane = tid & 63;
    const int w    = __builtin_amdgcn_readfirstlane(blockIdx.x * 4 + (tid >> 6));

    unsigned v[FAN_IN];          // current node's gathered pred values
    unsigned vn[FAN_IN];         // prefetch buffer (in flight most of the time)
    unsigned wmv  = 0;           // asm-loaded wm_page (valid after top drain)
    unsigned cohm = 0, cmn = 0;  // uniform coherent-path bitmasks (cur / next)
    int pend_pg = -1, pend_old = 0;

    int node = N_IN + w;         // first own node (N_TODO > NW always)

    // prologue: issue gather(first) into vn with wmn = N_IN
    {
        const long wb = (long)node * FAN_IN;
#pragma unroll
        for (int k = 0; k < FAN_IN; ++k) {
            const int id = in_ids[wb + k];
            const unsigned* p = vals + (long)id * NPAIR + lane;
            if (id < N_IN) {
                asm volatile("global_load_dword %0, %1, off"
                             : "=v"(vn[k]) : "v"(p));
            } else {
                asm volatile("global_load_dword %0, %1, off sc0 sc1"
                             : "=v"(vn[k]) : "v"(p));
                cmn |= 1u << k;
            }
        }
        asm volatile("global_load_dword %0, %1, off sc0 sc1"
                     : "=v"(wmv) : "v"(wm_page));
    }

    for (;;) {
        // single wait: drains prefetch(vn)+WM (issued one iter ago), prev
        // publish stores, and the page atomic before that.
        asm volatile("s_waitcnt vmcnt(0)" ::: "memory");
        __builtin_amdgcn_sched_barrier(0);

        // promote prefetch buffer to working buffer (registers, drained)
#pragma unroll
        for (int k = 0; k < FAN_IN; ++k) v[k] = vn[k];
        cohm = cmn;

        // deferred page-fill check (atomic issued last iter, drained now)
        if (pend_pg >= 0) {
            if (lane == 0) {
                const int ps = min(PGSZ, N_TODO - (pend_pg << PGSHIFT));
                if (pend_old + 1 == ps) wm_advance(wm_page, page_cnt);
            }
            pend_pg = -1;
        }
        // issue page atomic for PREVIOUS own node (its stores are drained)
        if (node - NW >= N_IN) {
            const int ppg = (node - NW - N_IN) >> PGSHIFT;
            if (lane == 0)
                pend_old = __hip_atomic_fetch_add(page_cnt + (size_t)ppg * PC_STRIDE, 1,
                                                  __ATOMIC_RELAXED,
                                                  __HIP_MEMORY_SCOPE_AGENT);
            pend_pg = ppg;
        }

        // WM for classifying the NEXT node's gather (one iter stale = safe)
        const int wmn = __builtin_amdgcn_readfirstlane((int)(N_IN + (wmv << PGSHIFT)));

        // issue prefetch gather(next) into vn NOW — hides under poll(cur)
        const int nxt = node + NW;
        cmn = 0;
        if (nxt < N_NODES) {
            const long wbn = (long)nxt * FAN_IN;
#pragma unroll
            for (int k = 0; k < FAN_IN; ++k) {
                const int id = in_ids[wbn + k];
                const unsigned* p = vals + (long)id * NPAIR + lane;
                if (id < wmn) {
                    asm volatile("global_load_dword %0, %1, off"
                                 : "=v"(vn[k]) : "v"(p));
                } else {
                    asm volatile("global_load_dword %0, %1, off sc0 sc1"
                                 : "=v"(vn[k]) : "v"(p));
                    cmn |= 1u << k;
                }
            }
            asm volatile("global_load_dword %0, %1, off sc0 sc1"
                         : "=v"(wmv) : "v"(wm_page));
        }

        const long wb = (long)node * FAN_IN;

        // sentinel poll over the coherent subset (irreducible dependency wait)
        unsigned need = cohm;
        while (need) {
            unsigned got = 0;
#pragma unroll
            for (int k = 0; k < FAN_IN; ++k)
                if ((need >> k) & 1u)
                    if (__all(v[k] != SENTW)) got |= 1u << k;
            need &= ~got;
            if (!need) break;
            __builtin_amdgcn_s_sleep(1);
#pragma unroll
            for (int k = 0; k < FAN_IN; ++k)
                if ((need >> k) & 1u) {
                    const int id = in_ids[wb + k];
                    v[k] = __hip_atomic_load(vals + (long)id * NPAIR + lane,
                                             __ATOMIC_RELAXED,
                                             __HIP_MEMORY_SCOPE_AGENT);
                }
        }

        // dot + relu in fp32 (weights uniform -> SGPR operand)
        float acc0 = 0.f, acc1 = 0.f;
#pragma unroll
        for (int k = 0; k < FAN_IN; ++k) {
            const float  wk = weights[wb + k];
            const __half2 h2 = *reinterpret_cast<const __half2*>(&v[k]);
            const float2  f  = __half22float2(h2);
            acc0 = fmaf(wk, f.x, acc0);
            acc1 = fmaf(wk, f.y, acc1);
        }
        acc0 = fmaxf(acc0, 0.f);
        acc1 = fmaxf(acc1, 0.f);

        // publish (agent-coherent write-through store; no drain here)
        __half2 hr = __floats2half2_rn(acc0, acc1);
        const unsigned ow = *reinterpret_cast<const unsigned*>(&hr);
        unsigned* orow = vals + (long)node * NPAIR + lane;
        asm volatile("global_store_dword %0, %1, off sc0 sc1"
                     :: "v"(orow), "v"(ow));

        // output-layer scatter
        if (node >= N_NODES - N_OUT) {
            const int jo = node - (N_NODES - N_OUT);
            out[lane * N_OUT + jo]        = acc0;
            out[(lane + 64) * N_OUT + jo] = acc1;
        }

        if (nxt >= N_NODES) break;
        node = nxt;
    }

    // epilogue: drain last publish, count last node, final WM checks
    asm volatile("s_waitcnt vmcnt(0)" ::: "memory");
    if (lane == 0) {
        if (pend_pg >= 0) {
            const int ps = min(PGSZ, N_TODO - (pend_pg << PGSHIFT));
            if (pend_old + 1 == ps) wm_advance(wm_page, page_cnt);
        }
        const int pg = (node - N_IN) >> PGSHIFT;
        const int ps = min(PGSZ, N_TODO - (pg << PGSHIFT));
        int old = __hip_atomic_fetch_add(page_cnt + (size_t)pg * PC_STRIDE, 1,
                                         __ATOMIC_RELAXED, __HIP_MEMORY_SCOPE_AGENT);
        if (old + 1 == ps) wm_advance(wm_page, page_cnt);
    }
}

extern "C" void kernel_launch(void* const* d_in, const int* in_sizes, int n_in,
                              void* d_out, int out_size, void* d_ws, size_t ws_size,
                              hipStream_t stream) {
    const float* x       = (const float*)d_in[0];
    const float* weights = (const float*)d_in[1];
    const int*   in_ids  = (const int*)d_in[2];
    float*       out     = (float*)d_out;

    int*      wm_page = (int*)((char*)d_ws + OFS_WM);
    int*      page_cnt= (int*)((char*)d_ws + OFS_PC);
    unsigned* vals    = (unsigned*)((char*)d_ws + OFS_VALS);

    init_kernel<<<2048, 256, 0, stream>>>(x, vals, wm_page, page_cnt);
    // 512 blocks x 4 waves = NW=2048 static owner waves; 2 blocks/CU
    // (0 LDS, ~120 VGPR, __launch_bounds__(256,2)) -> all waves resident.
    dag_kernel<<<NBLK, 256, 0, stream>>>(weights, in_ids, vals,
                                         wm_page, page_cnt, out);
}

// Round 11
// 524.666 us; speedup vs baseline: 5.3478x; 1.0759x over previous
//
#include <hip/hip_runtime.h>
#include <hip/hip_fp16.h>

// DAG phenotype evaluation: sentinel dataflow + watermark + static ownership
// + double-buffered prefetch-under-poll + DISTRIBUTED page counting (round 11).
//
// Round-10 measured 11.75 us/round == 1024 RMWs/line x ~11 ns on the 2 page-
// counter lines each round (round-5 calibration: ~11-15 ns per serialized
// same-line coherence-point RMW). Fix: two-level counters. Each page has 32
// sub-counter lines (g = wave&31; quota 32 per sub, 21 on the last page).
// Per-line RMW rate drops 32x. Sub-fillers increment subs_done[page] (rare),
// subs_done==32 -> CAS-advance WM. WM is replicated across 32 lines
// (readers use blockIdx&31; advancers rewrite all replicas - monotone, so
// last-writer-wins races only ever leave a LOWER value = safe lag).
//
// Everything else is round-10's proven structure:
//   - wave w of NW=2048 owns nodes N_IN + w + t*NW (48 rounds), all waves
//     resident (512 blocks, 2/CU, 0 LDS).
//   - per iteration ONE vmcnt(0) (drains prefetch issued an iter ago, prev
//     publish stores, prev sub atomic) + the irreducible dependency poll.
//   - preds < WM (stale = safe lower bound): PLAIN cached loads (L2);
//     preds >= WM: agent-coherent loads (sc0 sc1) + sentinel poll w/ backoff.
//   - publish: sc0 sc1 write-through store; sub atomic for node t issued at
//     top of iter t+1 (after the drain that retired t's publish stores);
//     its result checked at iter t+2.
//
// vals[N_NODES][64]: packed half2(b, b+64), 256 B/row; SENTW = NaN|NaN =
// "not ready" (no real value is NaN: inputs finite, outputs relu>=0).
//
// Deadlock-freedom: all 2048 waves resident; waves process own nodes in
// increasing order; lowest uncomputed node m: its owner's current node
// j <= m has all preds < j computed, so its poll terminates -> induction
// reaches m. WM lag cannot deadlock (polls are correct with WM == 0).

#define N_NODES 100000
#define N_IN    1024
#define N_OUT   1024
#define FAN_IN  32
#define NPAIR   64              // BATCH/2 packed slots per row
#define N_TODO  (N_NODES - N_IN)
#define SENTW   0xFFFFFFFFu
#define NW      2048            // static owner waves
#define NBLK    (NW / 4)        // 512 blocks
#define PGSZ    1024
#define PGSHIFT 10
#define NPAGES  ((N_TODO + PGSZ - 1) / PGSZ)   // 97
#define NSUB    32              // sub-counter lines per page
#define WMREP   32              // WM replica lines

// ws layout (bytes), every counter word on its own 256-B line:
//   [4096]    wm[32 replicas], stride 256 B (replica 0 = master)
//   [16384]   subs_done[97], stride 256 B
//   [65536]   sub_cnt[97*32], stride 256 B (794624 B)
//   [860160]  vals (25.6 MB)
#define OFS_WM    4096
#define OFS_SD    16384
#define OFS_SUB   65536
#define OFS_VALS  860160
#define LSTRIDE   64            // ints per 256-B line

__device__ __forceinline__ int subq(int pg) {
    return min(PGSZ, N_TODO - (pg << PGSHIFT)) >> 5;   // 32, last page 21
}

__global__ __launch_bounds__(256) void init_kernel(const float* __restrict__ x,
                                                   unsigned* __restrict__ vals,
                                                   int* __restrict__ wm,
                                                   int* __restrict__ subs_done,
                                                   int* __restrict__ sub_cnt) {
    const int tid = blockIdx.x * blockDim.x + threadIdx.x;
    if (tid < WMREP)        wm[tid * LSTRIDE] = 0;
    if (tid < NPAGES)       subs_done[tid * LSTRIDE] = 0;
    if (tid < NPAGES * NSUB) sub_cnt[tid * LSTRIDE] = 0;
    if (tid < N_IN * NPAIR) {
        const int i = tid >> 6;
        const int b = tid & 63;
        __half2 h2 = __floats2half2_rn(x[b * N_IN + i], x[(b + 64) * N_IN + i]);
        vals[i * NPAIR + b] = *reinterpret_cast<unsigned*>(&h2);
    }
    uint4* p = (uint4*)(vals + (size_t)N_IN * NPAIR);
    const int total = N_TODO * NPAIR / 4;
    const uint4 s4 = make_uint4(SENTW, SENTW, SENTW, SENTW);
    for (int t = tid; t < total; t += gridDim.x * blockDim.x)
        p[t] = s4;
}

__device__ __forceinline__ void wm_advance(int* wm, int* subs_done) {
    for (;;) {   // advance master WM over all consecutively-complete pages
        int cur = __hip_atomic_load(wm, __ATOMIC_RELAXED, __HIP_MEMORY_SCOPE_AGENT);
        if (cur >= NPAGES) break;
        int sd = __hip_atomic_load(subs_done + (size_t)cur * LSTRIDE,
                                   __ATOMIC_RELAXED, __HIP_MEMORY_SCOPE_AGENT);
        if (sd < NSUB) break;
        int expected = cur;
        __hip_atomic_compare_exchange_strong(wm, &expected, cur + 1,
                                             __ATOMIC_RELAXED, __ATOMIC_RELAXED,
                                             __HIP_MEMORY_SCOPE_AGENT);
    }
    // refresh replicas (monotone value; races only leave a lower = safe value)
    int fin = __hip_atomic_load(wm, __ATOMIC_RELAXED, __HIP_MEMORY_SCOPE_AGENT);
    for (int r = 1; r < WMREP; ++r)
        __hip_atomic_store(wm + (size_t)r * LSTRIDE, fin,
                           __ATOMIC_RELAXED, __HIP_MEMORY_SCOPE_AGENT);
}

__global__ __launch_bounds__(256, 2) void dag_kernel(const float* __restrict__ weights,
                                                     const int* __restrict__ in_ids,
                                                     unsigned* __restrict__ vals,
                                                     int* __restrict__ wm,
                                                     int* __restrict__ subs_done,
                                                     int* __restrict__ sub_cnt,
                                                     float* __restrict__ out) {
    const int tid  = threadIdx.x;
    const int lane = tid & 63;
    const int w    = __builtin_amdgcn_readfirstlane(blockIdx.x * 4 + (tid >> 6));
    const int g    = w & (NSUB - 1);                 // sub-counter group
    int* wm_rep    = wm + (size_t)(blockIdx.x & (WMREP - 1)) * LSTRIDE;

    unsigned v[FAN_IN];          // current node's gathered pred values
    unsigned vn[FAN_IN];         // prefetch buffer
    unsigned wmv  = 0;           // asm-loaded wm replica (valid after top drain)
    unsigned cohm = 0, cmn = 0;  // uniform coherent-path bitmasks (cur / next)
    int pend_pg = -1, pend_old = 0;

    int node = N_IN + w;         // first own node

    // prologue: issue gather(first) into vn with wmn = N_IN
    {
        const long wb = (long)node * FAN_IN;
#pragma unroll
        for (int k = 0; k < FAN_IN; ++k) {
            const int id = in_ids[wb + k];
            const unsigned* p = vals + (long)id * NPAIR + lane;
            if (id < N_IN) {
                asm volatile("global_load_dword %0, %1, off"
                             : "=v"(vn[k]) : "v"(p));
            } else {
                asm volatile("global_load_dword %0, %1, off sc0 sc1"
                             : "=v"(vn[k]) : "v"(p));
                cmn |= 1u << k;
            }
        }
        asm volatile("global_load_dword %0, %1, off sc0 sc1"
                     : "=v"(wmv) : "v"(wm_rep));
    }

    for (;;) {
        // single wait: drains prefetch(vn)+WM (issued one iter ago), prev
        // publish stores, and the sub atomic before that.
        asm volatile("s_waitcnt vmcnt(0)" ::: "memory");
        __builtin_amdgcn_sched_barrier(0);

        // promote prefetch buffer to working buffer
#pragma unroll
        for (int k = 0; k < FAN_IN; ++k) v[k] = vn[k];
        cohm = cmn;

        // deferred sub-fill check (atomic issued last iter, result drained)
        if (pend_pg >= 0) {
            if (lane == 0 && pend_old + 1 == subq(pend_pg)) {
                int sd = __hip_atomic_fetch_add(subs_done + (size_t)pend_pg * LSTRIDE, 1,
                                                __ATOMIC_RELAXED, __HIP_MEMORY_SCOPE_AGENT);
                if (sd + 1 == NSUB) wm_advance(wm, subs_done);
            }
            pend_pg = -1;
        }
        // issue sub atomic for PREVIOUS own node (its stores are drained)
        if (node - NW >= N_IN) {
            const int ppg = (node - NW - N_IN) >> PGSHIFT;
            if (lane == 0)
                pend_old = __hip_atomic_fetch_add(
                    sub_cnt + ((size_t)ppg * NSUB + g) * LSTRIDE, 1,
                    __ATOMIC_RELAXED, __HIP_MEMORY_SCOPE_AGENT);
            pend_pg = ppg;
        }

        // WM for classifying the NEXT node's gather (one iter stale = safe)
        const int wmn = __builtin_amdgcn_readfirstlane((int)(N_IN + (wmv << PGSHIFT)));

        // issue prefetch gather(next) into vn NOW — hides under poll(cur)
        const int nxt = node + NW;
        cmn = 0;
        if (nxt < N_NODES) {
            const long wbn = (long)nxt * FAN_IN;
#pragma unroll
            for (int k = 0; k < FAN_IN; ++k) {
                const int id = in_ids[wbn + k];
                const unsigned* p = vals + (long)id * NPAIR + lane;
                if (id < wmn) {
                    asm volatile("global_load_dword %0, %1, off"
                                 : "=v"(vn[k]) : "v"(p));
                } else {
                    asm volatile("global_load_dword %0, %1, off sc0 sc1"
                                 : "=v"(vn[k]) : "v"(p));
                    cmn |= 1u << k;
                }
            }
            asm volatile("global_load_dword %0, %1, off sc0 sc1"
                         : "=v"(wmv) : "v"(wm_rep));
        }

        const long wb = (long)node * FAN_IN;

        // sentinel poll over the coherent subset (irreducible dependency wait)
        unsigned need = cohm;
        while (need) {
            unsigned got = 0;
#pragma unroll
            for (int k = 0; k < FAN_IN; ++k)
                if ((need >> k) & 1u)
                    if (__all(v[k] != SENTW)) got |= 1u << k;
            need &= ~got;
            if (!need) break;
            __builtin_amdgcn_s_sleep(1);
#pragma unroll
            for (int k = 0; k < FAN_IN; ++k)
                if ((need >> k) & 1u) {
                    const int id = in_ids[wb + k];
                    v[k] = __hip_atomic_load(vals + (long)id * NPAIR + lane,
                                             __ATOMIC_RELAXED,
                                             __HIP_MEMORY_SCOPE_AGENT);
                }
        }

        // dot + relu in fp32 (weights uniform -> SGPR operand)
        float acc0 = 0.f, acc1 = 0.f;
#pragma unroll
        for (int k = 0; k < FAN_IN; ++k) {
            const float  wk = weights[wb + k];
            const __half2 h2 = *reinterpret_cast<const __half2*>(&v[k]);
            const float2  f  = __half22float2(h2);
            acc0 = fmaf(wk, f.x, acc0);
            acc1 = fmaf(wk, f.y, acc1);
        }
        acc0 = fmaxf(acc0, 0.f);
        acc1 = fmaxf(acc1, 0.f);

        // publish (agent-coherent write-through store; drained at next top)
        __half2 hr = __floats2half2_rn(acc0, acc1);
        const unsigned ow = *reinterpret_cast<const unsigned*>(&hr);
        unsigned* orow = vals + (long)node * NPAIR + lane;
        asm volatile("global_store_dword %0, %1, off sc0 sc1"
                     :: "v"(orow), "v"(ow));

        // output-layer scatter
        if (node >= N_NODES - N_OUT) {
            const int jo = node - (N_NODES - N_OUT);
            out[lane * N_OUT + jo]        = acc0;
            out[(lane + 64) * N_OUT + jo] = acc1;
        }

        if (nxt >= N_NODES) break;
        node = nxt;
    }

    // epilogue: drain last publish, flush pending + last node's count
    asm volatile("s_waitcnt vmcnt(0)" ::: "memory");
    if (lane == 0) {
        if (pend_pg >= 0 && pend_old + 1 == subq(pend_pg)) {
            int sd = __hip_atomic_fetch_add(subs_done + (size_t)pend_pg * LSTRIDE, 1,
                                            __ATOMIC_RELAXED, __HIP_MEMORY_SCOPE_AGENT);
            if (sd + 1 == NSUB) wm_advance(wm, subs_done);
        }
        const int pg = (node - N_IN) >> PGSHIFT;
        int old = __hip_atomic_fetch_add(sub_cnt + ((size_t)pg * NSUB + g) * LSTRIDE, 1,
                                         __ATOMIC_RELAXED, __HIP_MEMORY_SCOPE_AGENT);
        if (old + 1 == subq(pg)) {
            int sd = __hip_atomic_fetch_add(subs_done + (size_t)pg * LSTRIDE, 1,
                                            __ATOMIC_RELAXED, __HIP_MEMORY_SCOPE_AGENT);
            if (sd + 1 == NSUB) wm_advance(wm, subs_done);
        }
    }
}

extern "C" void kernel_launch(void* const* d_in, const int* in_sizes, int n_in,
                              void* d_out, int out_size, void* d_ws, size_t ws_size,
                              hipStream_t stream) {
    const float* x       = (const float*)d_in[0];
    const float* weights = (const float*)d_in[1];
    const int*   in_ids  = (const int*)d_in[2];
    float*       out     = (float*)d_out;

    int*      wm       = (int*)((char*)d_ws + OFS_WM);
    int*      subs_done= (int*)((char*)d_ws + OFS_SD);
    int*      sub_cnt  = (int*)((char*)d_ws + OFS_SUB);
    unsigned* vals     = (unsigned*)((char*)d_ws + OFS_VALS);

    init_kernel<<<2048, 256, 0, stream>>>(x, vals, wm, subs_done, sub_cnt);
    // 512 blocks x 4 waves = NW=2048 static owner waves; 2 blocks/CU
    // (0 LDS, __launch_bounds__(256,2)) -> all waves resident.
    dag_kernel<<<NBLK, 256, 0, stream>>>(weights, in_ids, vals,
                                         wm, subs_done, sub_cnt, out);
}